// Round 9
// baseline (277.371 us; speedup 1.0000x reference)
//
#include <hip/hip_runtime.h>

// SlotAttention on MI355X (gfx950).
// R8: gemm_kv with B-DIRECT fragments — weights (L2-resident, 4 MB) are
// loaded per-lane from global into registers (prefetched one K-tile ahead),
// bypassing LDS. LDS traffic per tile drops 72->48 KB (A-only staging+reads),
// moving the binding resource from LDS bandwidth to the MFMA pipe.
// Diagnosis: R5/R6 fit an LDS-BW model (90 B/cyc/CU) exactly; MFMA needs
// only 1242 of the 1600-cyc tile window. Skeleton = R5 (proven race-free,
// zero-conflict). cvt fused (R4); Q GEMM and attention unchanged.

#define TS 64
#define TD 4096
#define BATCH 8
#define HC 1024
#define NHEAD 16
#define MD (TD*BATCH)   // 32768
#define MS (TS*BATCH)   // 512
#define NCHUNK 8
#define CHTOK (TD/NCHUNK) // 512

typedef __attribute__((ext_vector_type(8))) __bf16 bf16x8;
typedef __attribute__((ext_vector_type(4))) float f32x4;
typedef __attribute__((ext_vector_type(4))) unsigned short u16x4;
typedef __attribute__((ext_vector_type(8))) unsigned short u16x8;

__device__ __forceinline__ unsigned short f2bf(float x){
  union { float f; unsigned u; } v; v.f = x;
  unsigned r = v.u + 0x7FFFu + ((v.u >> 16) & 1u);
  return (unsigned short)(r >> 16);
}

__device__ __forceinline__ void gll16(const void* g, void* l){
  __builtin_amdgcn_global_load_lds((__attribute__((address_space(1))) void*)g,
                                   (__attribute__((address_space(3))) void*)l, 16, 0, 0);
}

// Fused f32->bf16 convert for all five inputs (one launch).
__global__ void cvt_all(const float* __restrict__ d, const float* __restrict__ s,
                        const float* __restrict__ wq, const float* __restrict__ wk,
                        const float* __restrict__ wv,
                        unsigned short* __restrict__ dbf, unsigned short* __restrict__ sbf,
                        unsigned short* __restrict__ wqb, unsigned short* __restrict__ wkb,
                        unsigned short* __restrict__ wvb){
  long i = (long)blockIdx.x * 256 + threadIdx.x;
  const float* src; unsigned short* dst; long off;
  if (i < 8388608L)      { src = d;  dst = dbf; off = i; }
  else if (i < 8519680L) { src = s;  dst = sbf; off = i - 8388608L; }
  else if (i < 8781824L) { src = wq; dst = wqb; off = i - 8519680L; }
  else if (i < 9043968L) { src = wk; dst = wkb; off = i - 8781824L; }
  else                   { src = wv; dst = wvb; off = i - 9043968L; }
  f32x4 f = ((const f32x4*)src)[off];
  u16x4 o;
  o[0] = f2bf(f[0]); o[1] = f2bf(f[1]); o[2] = f2bf(f[2]); o[3] = f2bf(f[3]);
  ((u16x4*)dst)[off] = o;
}

// ---------------------------------------------------------------------------
// Fused K|V GEMM, B-direct version.
// C[32768 x 2048] = A @ [Wk;Wv]^T + bias. Tile 256x128, 4 waves (2Mx2N),
// per-wave 128x64, BK=32, grid 2048.
// A: staged in LDS (2 slots x 16KB, 64B rows, chunk^((row>>1)&3) swizzle —
//    R5-verified zero conflicts). B: per-lane global_load_dwordx4 into regs,
//    prefetched one tile ahead; the end-of-tile __syncthreads (vmcnt(0)
//    drain) makes them ready before use. No LDS for B.
// WAR/RAW: identical proof to R5 (stage into opposite slot; reads of that
// slot completed before the previous barrier).
// ---------------------------------------------------------------------------
__global__ __launch_bounds__(256, 2) void gemm_kv(
    const unsigned short* __restrict__ A,     // [32768][1024] bf16
    const unsigned short* __restrict__ Wkv,   // [2048][1024] bf16 (Wk rows, then Wv)
    const float* __restrict__ bk,
    const float* __restrict__ bv,
    unsigned short* __restrict__ Kout,
    unsigned short* __restrict__ Vout)
{
  __shared__ unsigned short As[2][256*32];   // 16 KB per slot

  const int nwg = gridDim.x;                 // 2048 (multiple of 8)
  const int cpx = nwg >> 3;
  const int orig = blockIdx.x;
  const int wg = (orig & 7) * cpx + (orig >> 3);   // bijective XCD swizzle
  const int mt = wg >> 4, nt = wg & 15;      // 128 x 16 tiles
  const int tid = threadIdx.x;
  const int lane = tid & 63, w = tid >> 6;   // 4 waves
  const int l15 = lane & 15, lg = lane >> 4;
  const int wm = w >> 1, wn = w & 1;

  // ---- A staging (R5 verbatim): 4 gll16/wave, 16 rows x 64B each.
  const int srow = lane >> 2;                               // 0..15
  const unsigned schunk = (unsigned)(((lane & 3) ^ ((lane >> 3) & 3)) << 4);
  const char* aS = (const char*)A + (size_t)(mt*256) * 2048 + schunk;
  const unsigned ar0 = (unsigned)((  0 + w*16 + srow) * 2048);
  const unsigned ar1 = (unsigned)(( 64 + w*16 + srow) * 2048);
  const unsigned ar2 = (unsigned)((128 + w*16 + srow) * 2048);
  const unsigned ar3 = (unsigned)((192 + w*16 + srow) * 2048);
  const unsigned da0 = (unsigned)((  0 + w*16) * 64);       // wave-uniform dests
  const unsigned da1 = (unsigned)(( 64 + w*16) * 64);
  const unsigned da2 = (unsigned)((128 + w*16) * 64);
  const unsigned da3 = (unsigned)((192 + w*16) * 64);

  #define STAGE_A(t_, buf_) { \
    const size_t ko = (size_t)(t_) * 64; \
    char* dA_ = (char*)&As[buf_][0]; \
    gll16(aS + ar0 + ko, dA_ + da0); \
    gll16(aS + ar1 + ko, dA_ + da1); \
    gll16(aS + ar2 + ko, dA_ + da2); \
    gll16(aS + ar3 + ko, dA_ + da3); \
    __builtin_amdgcn_sched_barrier(0); }

  // ---- B direct-load base: lane covers W row nt*128 + wn*64 + nf*16 + l15,
  // bytes [t*64 + lg*16, +16).
  const char* bgl = (const char*)Wkv
      + (size_t)(nt*128 + wn*64 + l15) * 2048 + (unsigned)(lg*16);

  #define LOAD_B(dst_, t_) { \
    _Pragma("unroll") \
    for (int nf = 0; nf < 4; ++nf) \
      dst_[nf] = *(const bf16x8*)(bgl + (size_t)nf*16*2048 + (size_t)(t_)*64); }

  // ---- A fragment read offsets (R5 verbatim)
  const unsigned ksel = (unsigned)((lg ^ ((l15 >> 1) & 3)) << 4);
  const unsigned aoff = (unsigned)(wm*128 + l15) * 64 + ksel;   // + mf*1024

  const f32x4 fz = {0.f, 0.f, 0.f, 0.f};
  f32x4 acc[8][4];
  #pragma unroll
  for (int m = 0; m < 8; ++m)
    #pragma unroll
    for (int n = 0; n < 4; ++n) acc[m][n] = fz;

  #define TILE(buf_, bfr_) { \
    const char* as_ = (const char*)&As[buf_][0]; \
    bf16x8 af[8]; \
    _Pragma("unroll") \
    for (int m = 0; m < 8; ++m) af[m] = *(const bf16x8*)(as_ + aoff + m*1024u); \
    __builtin_amdgcn_s_setprio(1); \
    _Pragma("unroll") \
    for (int m = 0; m < 8; ++m) \
      _Pragma("unroll") \
      for (int n = 0; n < 4; ++n) \
        acc[m][n] = __builtin_amdgcn_mfma_f32_16x16x32_bf16(af[m], bfr_[n], acc[m][n], 0, 0, 0); \
    __builtin_amdgcn_s_setprio(0); }

  bf16x8 bA[4], bB[4];

  // ---- prologue: B(0) + A(0); barrier drains both.
  LOAD_B(bA, 0)
  STAGE_A(0, 0)
  __syncthreads();

  // ---- main loop: 32 K-tiles, 2 per iteration (static names)
  #pragma unroll 1
  for (int tp = 0; tp < 16; ++tp){
    LOAD_B(bB, 2*tp + 1)           // B for odd tile -> regs
    STAGE_A(2*tp + 1, 1)           // A for odd tile -> slot 1
    TILE(0, bA)                    // compute even tile
    __syncthreads();               // drains B(odd) + A(odd)
    if (tp < 15){
      LOAD_B(bA, 2*tp + 2)
      STAGE_A(2*tp + 2, 0)
    }
    TILE(1, bB)
    __syncthreads();
  }

  // ---- epilogue: bias + bf16 store (block's 128 cols uniformly K or V)
  const int ccol = (nt & 7)*128 + wn*64;
  unsigned short* Cb = (nt < 8) ? Kout : Vout;
  const float* bias = (nt < 8) ? bk : bv;
  float bvv[4];
  #pragma unroll
  for (int nf = 0; nf < 4; ++nf) bvv[nf] = bias[ccol + nf*16 + l15];
  #pragma unroll
  for (int mf = 0; mf < 8; ++mf){
    #pragma unroll
    for (int r = 0; r < 4; ++r){
      size_t row = (size_t)(mt*256 + wm*128 + mf*16 + lg*4 + r);
      unsigned short* cp = Cb + row*1024 + ccol;
      #pragma unroll
      for (int nf = 0; nf < 4; ++nf)
        cp[nf*16 + l15] = f2bf(acc[mf][nf][r] + bvv[nf]);
    }
  }
  #undef STAGE_A
  #undef LOAD_B
  #undef TILE
}

// ---------------------------------------------------------------------------
// 128^2 GEMM kept for Q (M=512): verified in R0.
// ---------------------------------------------------------------------------
__global__ __launch_bounds__(256) void gemm128(
    const unsigned short* __restrict__ A,
    const unsigned short* __restrict__ W,
    const float* __restrict__ bias,
    unsigned short* __restrict__ C)
{
  __shared__ unsigned short As[128*64];
  __shared__ unsigned short Bs[128*64];
  const int nwg = gridDim.x;
  const int cpx = nwg >> 3;
  const int orig = blockIdx.x;
  const int wg = (orig & 7) * cpx + (orig >> 3);
  const int mt = wg >> 3, nt = wg & 7;
  const int tid = threadIdx.x;
  const int lane = tid & 63, w = tid >> 6;
  const int l15 = lane & 15, lg = lane >> 4;
  const int wr = w >> 1, wc = w & 1;

  const int lrow = lane >> 3;
  const int lch  = (lane & 7) << 4;
  const char* pA[4]; const char* pB[4]; unsigned ldsoff[4];
  #pragma unroll
  for (int j = 0; j < 4; ++j){
    int row = w*32 + j*8 + lrow;
    int sw  = lch ^ ((row & 7) << 4);
    pA[j] = (const char*)A + (size_t)(mt*128 + row) * 2048 + sw;
    pB[j] = (const char*)W + (size_t)(nt*128 + row) * 2048 + sw;
    ldsoff[j] = (unsigned)(w*32 + j*8) * 128;
  }

  const f32x4 fz = {0.f, 0.f, 0.f, 0.f};
  f32x4 acc[4][4];
  #pragma unroll
  for (int m = 0; m < 4; ++m)
    #pragma unroll
    for (int n = 0; n < 4; ++n) acc[m][n] = fz;

  for (int kt = 0; kt < 16; ++kt){
    __syncthreads();
    #pragma unroll
    for (int j = 0; j < 4; ++j){
      gll16(pA[j] + (size_t)kt*128, (char*)As + ldsoff[j]);
      gll16(pB[j] + (size_t)kt*128, (char*)Bs + ldsoff[j]);
    }
    __syncthreads();
    #pragma unroll
    for (int kk = 0; kk < 2; ++kk){
      bf16x8 af[4], bfr[4];
      #pragma unroll
      for (int m = 0; m < 4; ++m){
        int row = wr*64 + m*16 + l15;
        af[m] = *(const bf16x8*)((const char*)As + row*128 + ((lg*16 + kk*64) ^ ((row & 7) << 4)));
      }
      #pragma unroll
      for (int n = 0; n < 4; ++n){
        int row = wc*64 + n*16 + l15;
        bfr[n] = *(const bf16x8*)((const char*)Bs + row*128 + ((lg*16 + kk*64) ^ ((row & 7) << 4)));
      }
      #pragma unroll
      for (int m = 0; m < 4; ++m)
        #pragma unroll
        for (int n = 0; n < 4; ++n)
          acc[m][n] = __builtin_amdgcn_mfma_f32_16x16x32_bf16(af[m], bfr[n], acc[m][n], 0, 0, 0);
    }
  }

  const int ccol0 = nt*128 + wc*64;
  float bv[4];
  #pragma unroll
  for (int n = 0; n < 4; ++n) bv[n] = bias[ccol0 + n*16 + l15];
  #pragma unroll
  for (int m = 0; m < 4; ++m){
    #pragma unroll
    for (int r = 0; r < 4; ++r){
      size_t row = (size_t)(mt*128 + wr*64 + m*16 + lg*4 + r);
      unsigned short* cp = C + row*1024 + ccol0;
      #pragma unroll
      for (int n = 0; n < 4; ++n)
        cp[n*16 + l15] = f2bf(acc[m][n][r] + bv[n]);
    }
  }
}

// one block per (b*16+h, chunk). 256 threads = 4 waves; wave w owns slots [16w,16w+16).
__global__ __launch_bounds__(256) void attn_kernel(
    const unsigned short* __restrict__ Q,
    const unsigned short* __restrict__ K,
    const unsigned short* __restrict__ V,
    float* __restrict__ P)
{
  __shared__ unsigned short Qs[64*64];
  __shared__ unsigned short Ks[64*64];
  __shared__ unsigned short Vt[80*64];
  __shared__ unsigned short Al[64*64];
  __shared__ float red[256];

  const int bh = blockIdx.x;
  const int chunk = blockIdx.y;
  const int bb = bh >> 4, h = bh & 15;
  const int tid = threadIdx.x;
  const int lane = tid & 63, w = tid >> 6;
  const int l15 = lane & 15, lg = lane >> 4;
  const int lrow = lane >> 3, lch = (lane & 7) << 4;

  for (int i = tid; i < 16*64; i += 256){
    int r = i >> 6;
    Vt[(64 + r)*64 + (i & 63)] = (r == 0) ? (unsigned short)0x3F80 : (unsigned short)0;
  }

  #pragma unroll
  for (int j = 0; j < 2; ++j){
    int row = w*16 + j*8 + lrow;
    int sw = lch ^ ((row & 7) << 4);
    const char* g = (const char*)Q + (size_t)(row*BATCH + bb)*2048 + h*128 + sw;
    gll16(g, (char*)Qs + (w*16 + j*8)*128);
  }

  const f32x4 fz = {0.f, 0.f, 0.f, 0.f};
  f32x4 acc[5];
  #pragma unroll
  for (int nb = 0; nb < 5; ++nb) acc[nb] = fz;

  const int vtok = tid >> 2;
  const int vcg  = tid & 3;
  const int t0 = chunk * CHTOK;

  for (int tt = 0; tt < CHTOK/64; ++tt){
    const int tb = t0 + tt*64;
    #pragma unroll
    for (int j = 0; j < 2; ++j){
      int row = w*16 + j*8 + lrow;
      int sw = lch ^ ((row & 7) << 4);
      const char* g = (const char*)K + (size_t)((size_t)(tb + row)*BATCH + bb)*2048 + h*128 + sw;
      gll16(g, (char*)Ks + (w*16 + j*8)*128);
    }
    const char* vg = (const char*)V + (size_t)((size_t)(tb + vtok)*BATCH + bb)*2048 + h*128 + vcg*32;
    u16x8 v0 = *(const u16x8*)vg;
    u16x8 v1 = *(const u16x8*)(vg + 16);
    __syncthreads();

    bf16x8 qa[2];
    #pragma unroll
    for (int kk = 0; kk < 2; ++kk){
      int row = w*16 + l15;
      qa[kk] = *(const bf16x8*)((const char*)Qs + row*128 + ((lg*16 + kk*64) ^ ((row & 7) << 4)));
    }
    float e[4][4];
    #pragma unroll
    for (int nb = 0; nb < 4; ++nb){
      f32x4 s = fz;
      #pragma unroll
      for (int kk = 0; kk < 2; ++kk){
        int row = nb*16 + l15;
        bf16x8 kb = *(const bf16x8*)((const char*)Ks + row*128 + ((lg*16 + kk*64) ^ ((row & 7) << 4)));
        s = __builtin_amdgcn_mfma_f32_16x16x32_bf16(qa[kk], kb, s, 0, 0, 0);
      }
      #pragma unroll
      for (int r = 0; r < 4; ++r) e[nb][r] = __expf(s[r] * 0.125f);
    }
    #pragma unroll
    for (int nb = 0; nb < 4; ++nb){
      float cp = e[nb][0] + e[nb][1] + e[nb][2] + e[nb][3];
      cp += __shfl_xor(cp, 16);
      cp += __shfl_xor(cp, 32);
      if (lg == 0) red[w*64 + nb*16 + l15] = cp;
    }
    __syncthreads();

    #pragma unroll
    for (int nb = 0; nb < 4; ++nb){
      int col = nb*16 + l15;
      float dn = red[col] + red[64 + col] + red[128 + col] + red[192 + col];
      float inv = 1.0f / dn;
      #pragma unroll
      for (int r = 0; r < 4; ++r){
        int row = w*16 + lg*4 + r;
        Al[row*64 + ((((2*col)) ^ ((row & 7) << 4)) >> 1)] = f2bf(e[nb][r] * inv);
      }
    }
    #pragma unroll
    for (int ee = 0; ee < 8; ++ee){
      int c0 = vcg*16 + ee;
      int sw0 = (((c0 & 7) ^ (c0 >> 3)) & 7) << 4;
      Vt[c0*64 + (((2*vtok) ^ sw0) >> 1)] = v0[ee];
    }
    #pragma unroll
    for (int ee = 0; ee < 8; ++ee){
      int c1 = vcg*16 + 8 + ee;
      int sw1 = (((c1 & 7) ^ (c1 >> 3)) & 7) << 4;
      Vt[c1*64 + (((2*vtok) ^ sw1) >> 1)] = v1[ee];
    }
    __syncthreads();

    bf16x8 aa[2];
    #pragma unroll
    for (int kk = 0; kk < 2; ++kk){
      int row = w*16 + l15;
      aa[kk] = *(const bf16x8*)((const char*)Al + row*128 + ((lg*16 + kk*64) ^ ((row & 7) << 4)));
    }
    #pragma unroll
    for (int nb = 0; nb < 5; ++nb){
      #pragma unroll
      for (int kk = 0; kk < 2; ++kk){
        int row = nb*16 + l15;
        int sw = (((row & 7) ^ (row >> 3)) & 7) << 4;
        bf16x8 vb = *(const bf16x8*)((const char*)Vt + row*128 + ((lg*16 + kk*64) ^ sw));
        acc[nb] = __builtin_amdgcn_mfma_f32_16x16x32_bf16(aa[kk], vb, acc[nb], 0, 0, 0);
      }
    }
  }

  float* Pb = P + (size_t)(bh*NCHUNK + chunk) * 64 * 80;
  #pragma unroll
  for (int nb = 0; nb < 5; ++nb){
    #pragma unroll
    for (int r = 0; r < 4; ++r){
      int s = w*16 + lg*4 + r;
      Pb[(size_t)s*80 + nb*16 + l15] = acc[nb][r];
    }
  }
}

__global__ void reduce_out(const float* __restrict__ P, float* __restrict__ out){
  int flat = blockIdx.x * 256 + threadIdx.x;
  int c = flat & 63, s = (flat >> 6) & 63, bh = flat >> 12;
  int bb = bh >> 4, h = bh & 15;
  float sc = 0.f, sn = 0.f;
  #pragma unroll
  for (int ch = 0; ch < NCHUNK; ++ch){
    const float* base = P + ((size_t)(bh*NCHUNK + ch)*64 + s)*80;
    sc += base[c];
    sn += base[64];
  }
  out[((size_t)s*BATCH + bb)*1024 + h*64 + c] = sc / (sn + 0.001f);
}

extern "C" void kernel_launch(void* const* d_in, const int* in_sizes, int n_in,
                              void* d_out, int out_size, void* d_ws, size_t ws_size,
                              hipStream_t stream)
{
  const float* s  = (const float*)d_in[0];
  const float* d  = (const float*)d_in[1];
  const float* Wq = (const float*)d_in[2];
  const float* bq = (const float*)d_in[3];
  const float* Wk = (const float*)d_in[4];
  const float* bk = (const float*)d_in[5];
  const float* Wv = (const float*)d_in[6];
  const float* bv = (const float*)d_in[7];
  float* out = (float*)d_out;

  char* ws = (char*)d_ws;
  unsigned short* dbf = (unsigned short*)(ws);               // 67,108,864
  unsigned short* sbf = (unsigned short*)(ws + 67108864);    //  1,048,576
  unsigned short* wqb = (unsigned short*)(ws + 68157440);    //  2,097,152
  unsigned short* wkb = (unsigned short*)(ws + 70254592);    //  2,097,152 (Wk rows 0..1023)
  unsigned short* wvb = (unsigned short*)(ws + 72351744);    //  2,097,152 (Wv rows = wkb rows 1024..2047)
  unsigned short* Qw  = (unsigned short*)(ws + 74448896);    //  1,048,576
  unsigned short* Kw  = (unsigned short*)(ws + 75497472);    // 67,108,864
  unsigned short* Vw  = (unsigned short*)(ws + 142606336);   // 67,108,864
  float*          Pw  = (float*)(ws + 209715200);            // 20,971,520

  (void)in_sizes; (void)n_in; (void)out_size; (void)ws_size;

  cvt_all<<<36352, 256, 0, stream>>>(d, s, Wq, Wk, Wv, dbf, sbf, wqb, wkb, wvb);

  gemm128<<<(MS/128)*8, 256, 0, stream>>>(sbf, wqb, bq, Qw);
  gemm_kv<<<(MD/256)*16, 256, 0, stream>>>(dbf, wkb, bk, bv, Kw, Vw);

  attn_kernel<<<dim3(128, NCHUNK), 256, 0, stream>>>(Qw, Kw, Vw, Pw);

  reduce_out<<<(TS*BATCH*HC)/256, 256, 0, stream>>>(Pw, out);
}

// Round 10
// 253.984 us; speedup vs baseline: 1.0921x; 1.0921x over previous
//
#include <hip/hip_runtime.h>

// SlotAttention on MI355X (gfx950).
// R9: A-reuse at the right occupancy. gemm_kvq: tile 128x256 where N spans
// the K-half AND V-half of [Wk;Wv] -> A staged once for both projections
// (L3-read traffic halves vs R5), while keeping the 4-wave / acc-128 /
// 48 KB-LDS shape that actually achieves 2 blocks/CU (R7's 8-wave version
// was silently register-capped to 1 block/CU). Q GEMM merged as 16 extra
// blocks. Schedule + swizzle = R5's proven race-free zero-conflict pattern.

#define TS 64
#define TD 4096
#define BATCH 8
#define HC 1024
#define NHEAD 16
#define MD (TD*BATCH)   // 32768
#define MS (TS*BATCH)   // 512
#define NCHUNK 8
#define CHTOK (TD/NCHUNK) // 512

typedef __attribute__((ext_vector_type(8))) __bf16 bf16x8;
typedef __attribute__((ext_vector_type(4))) float f32x4;
typedef __attribute__((ext_vector_type(4))) unsigned short u16x4;
typedef __attribute__((ext_vector_type(8))) unsigned short u16x8;

__device__ __forceinline__ unsigned short f2bf(float x){
  union { float f; unsigned u; } v; v.f = x;
  unsigned r = v.u + 0x7FFFu + ((v.u >> 16) & 1u);
  return (unsigned short)(r >> 16);
}

__device__ __forceinline__ void gll16(const void* g, void* l){
  __builtin_amdgcn_global_load_lds((__attribute__((address_space(1))) void*)g,
                                   (__attribute__((address_space(3))) void*)l, 16, 0, 0);
}

// Fused f32->bf16 convert for all five inputs (one launch).
__global__ void cvt_all(const float* __restrict__ d, const float* __restrict__ s,
                        const float* __restrict__ wq, const float* __restrict__ wk,
                        const float* __restrict__ wv,
                        unsigned short* __restrict__ dbf, unsigned short* __restrict__ sbf,
                        unsigned short* __restrict__ wqb, unsigned short* __restrict__ wkb,
                        unsigned short* __restrict__ wvb){
  long i = (long)blockIdx.x * 256 + threadIdx.x;
  const float* src; unsigned short* dst; long off;
  if (i < 8388608L)      { src = d;  dst = dbf; off = i; }
  else if (i < 8519680L) { src = s;  dst = sbf; off = i - 8388608L; }
  else if (i < 8781824L) { src = wq; dst = wqb; off = i - 8519680L; }
  else if (i < 9043968L) { src = wk; dst = wkb; off = i - 8781824L; }
  else                   { src = wv; dst = wvb; off = i - 9043968L; }
  f32x4 f = ((const f32x4*)src)[off];
  u16x4 o;
  o[0] = f2bf(f[0]); o[1] = f2bf(f[1]); o[2] = f2bf(f[2]); o[3] = f2bf(f[3]);
  ((u16x4*)dst)[off] = o;
}

// ---------------------------------------------------------------------------
// Unified QKV GEMM with A-reuse.
// kv-role (blocks 0..2047): tile 128x256 of [K | V]: A rows [mt*128,+128) of
//   dbf; output cols = Kout[:, nt*128..+128) (wn=0) and Vout[:, nt*128..+128)
//   (wn=1). B-tile local rows 0..127 = Wk rows nt*128.., 128..255 = Wv rows
//   (Wkv rows 1024+nt*128..). A staged ONCE feeds both projections.
// q-role (blocks 2048..2063): tile 128x256 of Q: A = sbf rows [mt*128,+128),
//   B = Wq rows [nt*256,+256).
// 4 waves (2M x 2N), per-wave 64x128 (acc[4][8] = 128 AGPR), BK=32.
// LDS: (A 8KB + B 16KB) x 2 slots = 48KB -> 2 blocks/CU at ~236 regs/wave.
// Per K-tile: 6 gll16/wave staged into opposite slot (issued first), then
// 12 ds_read_b128 + 32 MFMA, one __syncthreads. R5 swizzle (0 conflicts).
// ---------------------------------------------------------------------------
__global__ __launch_bounds__(256, 2) void gemm_kvq(
    const unsigned short* __restrict__ A,     // dbf [32768][1024]
    const unsigned short* __restrict__ Sb,    // sbf [512][1024]
    const unsigned short* __restrict__ Wkv,   // [2048][1024] (Wk rows, then Wv)
    const unsigned short* __restrict__ Wq,    // [1024][1024]
    const float* __restrict__ bq,
    const float* __restrict__ bk,
    const float* __restrict__ bv,
    unsigned short* __restrict__ Qout,
    unsigned short* __restrict__ Kout,
    unsigned short* __restrict__ Vout)
{
  __shared__ unsigned short As[2][128*32];   //  8 KB per slot
  __shared__ unsigned short Bs[2][256*32];   // 16 KB per slot

  const int nwg = gridDim.x;                 // 2064 (multiple of 8)
  const int cpx = nwg >> 3;                  // 258
  const int orig = blockIdx.x;
  const int wg = (orig & 7) * cpx + (orig >> 3);   // bijective XCD swizzle
  const int tid = threadIdx.x;
  const int lane = tid & 63, w = tid >> 6;   // 4 waves
  const int l15 = lane & 15, lg = lane >> 4;
  const int wm = w >> 1, wn = w & 1;

  const bool isQ = (wg >= 2048);
  int mt, nt;
  const unsigned short* Ab; const unsigned short* Bb;
  if (!isQ){ mt = wg >> 3; nt = wg & 7; Ab = A;  Bb = Wkv; }
  else     { int qi = wg - 2048; mt = qi >> 2; nt = qi & 3; Ab = Sb; Bb = Wq; }

  // ---- staging addressing: each gll16 covers 16 rows x 64B (R5 pattern).
  // lane: row-in-group = lane>>2, chunk pos = lane&3, src chunk pre-swizzled
  // by ((lane>>3)&3) == ((row-in-group)>>1)&3.
  const int r16 = lane >> 2;                                // 0..15
  const unsigned schunk = (unsigned)(((lane & 3) ^ ((lane >> 3) & 3)) << 4);
  const char* aS = (const char*)(Ab + (size_t)mt*128*1024) + schunk;
  const char* bS = (const char*)Bb + schunk;

  unsigned a_src[2]; unsigned a_dst[2];
  #pragma unroll
  for (int j = 0; j < 2; ++j){
    int lr = w*32 + j*16 + r16;                             // 0..127
    a_src[j] = (unsigned)(lr * 2048);
    a_dst[j] = (unsigned)((w*32 + j*16) * 64);              // wave-uniform
  }
  size_t b_src[4]; unsigned b_dst[4];
  #pragma unroll
  for (int j = 0; j < 4; ++j){
    int lb = w*64 + j*16 + r16;                             // 0..255
    int grow;
    if (isQ)           grow = nt*256 + lb;
    else if (lb < 128) grow = nt*128 + lb;                  // Wk half
    else               grow = 1024 + nt*128 + (lb - 128);   // Wv half
    b_src[j] = (size_t)grow * 2048;
    b_dst[j] = (unsigned)((w*64 + j*16) * 64);
  }

  #define STAGE(t_, buf_) { \
    const size_t ko = (size_t)(t_) * 64; \
    char* dA_ = (char*)&As[buf_][0]; char* dB_ = (char*)&Bs[buf_][0]; \
    gll16(aS + a_src[0] + ko, dA_ + a_dst[0]); \
    gll16(aS + a_src[1] + ko, dA_ + a_dst[1]); \
    gll16(bS + b_src[0] + ko, dB_ + b_dst[0]); \
    gll16(bS + b_src[1] + ko, dB_ + b_dst[1]); \
    gll16(bS + b_src[2] + ko, dB_ + b_dst[2]); \
    gll16(bS + b_src[3] + ko, dB_ + b_dst[3]); \
    __builtin_amdgcn_sched_barrier(0); }

  // ---- fragment read offsets (R5 family: 64B rows, chunk XOR (row>>1)&3)
  const unsigned ksel = (unsigned)((lg ^ ((l15 >> 1) & 3)) << 4);
  const unsigned aoff = (unsigned)(wm*64  + l15) * 64 + ksel;   // + mf*1024
  const unsigned boff = (unsigned)(wn*128 + l15) * 64 + ksel;   // + nf*1024

  const f32x4 fz = {0.f, 0.f, 0.f, 0.f};
  f32x4 acc[4][8];
  #pragma unroll
  for (int m = 0; m < 4; ++m)
    #pragma unroll
    for (int n = 0; n < 8; ++n) acc[m][n] = fz;

  #define TILE(buf_) { \
    const char* as_ = (const char*)&As[buf_][0]; \
    const char* bs_ = (const char*)&Bs[buf_][0]; \
    bf16x8 af[4], bfr[8]; \
    _Pragma("unroll") \
    for (int m = 0; m < 4; ++m) af[m] = *(const bf16x8*)(as_ + aoff + m*1024u); \
    _Pragma("unroll") \
    for (int n = 0; n < 8; ++n) bfr[n] = *(const bf16x8*)(bs_ + boff + n*1024u); \
    __builtin_amdgcn_s_setprio(1); \
    _Pragma("unroll") \
    for (int m = 0; m < 4; ++m) \
      _Pragma("unroll") \
      for (int n = 0; n < 8; ++n) \
        acc[m][n] = __builtin_amdgcn_mfma_f32_16x16x32_bf16(af[m], bfr[n], acc[m][n], 0, 0, 0); \
    __builtin_amdgcn_s_setprio(0); }

  // ---- prologue
  STAGE(0, 0)
  __syncthreads();

  // ---- main loop: 32 K-tiles, 2 per iteration (static slot indices)
  #pragma unroll 1
  for (int tp = 0; tp < 16; ++tp){
    STAGE(2*tp + 1, 1)         // next tile -> slot 1 (reads of slot1 done last iter)
    TILE(0)
    __syncthreads();           // drains slot-1 staging; all waves aligned
    if (tp < 15) STAGE(2*tp + 2, 0)
    TILE(1)
    __syncthreads();
  }

  // ---- epilogue: bias + bf16 store. kv: wn=0 -> K cols, wn=1 -> V cols.
  int ccol; unsigned short* Cb; const float* bias;
  if (isQ){ Cb = Qout; bias = bq; ccol = nt*256 + wn*128; }
  else    { Cb = wn ? Vout : Kout; bias = wn ? bv : bk; ccol = nt*128; }
  float bvv[8];
  #pragma unroll
  for (int nf = 0; nf < 8; ++nf) bvv[nf] = bias[ccol + nf*16 + l15];
  #pragma unroll
  for (int mf = 0; mf < 4; ++mf){
    #pragma unroll
    for (int r = 0; r < 4; ++r){
      size_t row = (size_t)(mt*128 + wm*64 + mf*16 + lg*4 + r);
      unsigned short* cp = Cb + row*1024 + ccol;
      #pragma unroll
      for (int nf = 0; nf < 8; ++nf)
        cp[nf*16 + l15] = f2bf(acc[mf][nf][r] + bvv[nf]);
    }
  }
  #undef STAGE
  #undef TILE
}

// one block per (b*16+h, chunk). 256 threads = 4 waves; wave w owns slots [16w,16w+16).
__global__ __launch_bounds__(256) void attn_kernel(
    const unsigned short* __restrict__ Q,
    const unsigned short* __restrict__ K,
    const unsigned short* __restrict__ V,
    float* __restrict__ P)
{
  __shared__ unsigned short Qs[64*64];
  __shared__ unsigned short Ks[64*64];
  __shared__ unsigned short Vt[80*64];
  __shared__ unsigned short Al[64*64];
  __shared__ float red[256];

  const int bh = blockIdx.x;
  const int chunk = blockIdx.y;
  const int bb = bh >> 4, h = bh & 15;
  const int tid = threadIdx.x;
  const int lane = tid & 63, w = tid >> 6;
  const int l15 = lane & 15, lg = lane >> 4;
  const int lrow = lane >> 3, lch = (lane & 7) << 4;

  for (int i = tid; i < 16*64; i += 256){
    int r = i >> 6;
    Vt[(64 + r)*64 + (i & 63)] = (r == 0) ? (unsigned short)0x3F80 : (unsigned short)0;
  }

  #pragma unroll
  for (int j = 0; j < 2; ++j){
    int row = w*16 + j*8 + lrow;
    int sw = lch ^ ((row & 7) << 4);
    const char* g = (const char*)Q + (size_t)(row*BATCH + bb)*2048 + h*128 + sw;
    gll16(g, (char*)Qs + (w*16 + j*8)*128);
  }

  const f32x4 fz = {0.f, 0.f, 0.f, 0.f};
  f32x4 acc[5];
  #pragma unroll
  for (int nb = 0; nb < 5; ++nb) acc[nb] = fz;

  const int vtok = tid >> 2;
  const int vcg  = tid & 3;
  const int t0 = chunk * CHTOK;

  for (int tt = 0; tt < CHTOK/64; ++tt){
    const int tb = t0 + tt*64;
    #pragma unroll
    for (int j = 0; j < 2; ++j){
      int row = w*16 + j*8 + lrow;
      int sw = lch ^ ((row & 7) << 4);
      const char* g = (const char*)K + (size_t)((size_t)(tb + row)*BATCH + bb)*2048 + h*128 + sw;
      gll16(g, (char*)Ks + (w*16 + j*8)*128);
    }
    const char* vg = (const char*)V + (size_t)((size_t)(tb + vtok)*BATCH + bb)*2048 + h*128 + vcg*32;
    u16x8 v0 = *(const u16x8*)vg;
    u16x8 v1 = *(const u16x8*)(vg + 16);
    __syncthreads();

    bf16x8 qa[2];
    #pragma unroll
    for (int kk = 0; kk < 2; ++kk){
      int row = w*16 + l15;
      qa[kk] = *(const bf16x8*)((const char*)Qs + row*128 + ((lg*16 + kk*64) ^ ((row & 7) << 4)));
    }
    float e[4][4];
    #pragma unroll
    for (int nb = 0; nb < 4; ++nb){
      f32x4 s = fz;
      #pragma unroll
      for (int kk = 0; kk < 2; ++kk){
        int row = nb*16 + l15;
        bf16x8 kb = *(const bf16x8*)((const char*)Ks + row*128 + ((lg*16 + kk*64) ^ ((row & 7) << 4)));
        s = __builtin_amdgcn_mfma_f32_16x16x32_bf16(qa[kk], kb, s, 0, 0, 0);
      }
      #pragma unroll
      for (int r = 0; r < 4; ++r) e[nb][r] = __expf(s[r] * 0.125f);
    }
    #pragma unroll
    for (int nb = 0; nb < 4; ++nb){
      float cp = e[nb][0] + e[nb][1] + e[nb][2] + e[nb][3];
      cp += __shfl_xor(cp, 16);
      cp += __shfl_xor(cp, 32);
      if (lg == 0) red[w*64 + nb*16 + l15] = cp;
    }
    __syncthreads();

    #pragma unroll
    for (int nb = 0; nb < 4; ++nb){
      int col = nb*16 + l15;
      float dn = red[col] + red[64 + col] + red[128 + col] + red[192 + col];
      float inv = 1.0f / dn;
      #pragma unroll
      for (int r = 0; r < 4; ++r){
        int row = w*16 + lg*4 + r;
        Al[row*64 + ((((2*col)) ^ ((row & 7) << 4)) >> 1)] = f2bf(e[nb][r] * inv);
      }
    }
    #pragma unroll
    for (int ee = 0; ee < 8; ++ee){
      int c0 = vcg*16 + ee;
      int sw0 = (((c0 & 7) ^ (c0 >> 3)) & 7) << 4;
      Vt[c0*64 + (((2*vtok) ^ sw0) >> 1)] = v0[ee];
    }
    #pragma unroll
    for (int ee = 0; ee < 8; ++ee){
      int c1 = vcg*16 + 8 + ee;
      int sw1 = (((c1 & 7) ^ (c1 >> 3)) & 7) << 4;
      Vt[c1*64 + (((2*vtok) ^ sw1) >> 1)] = v1[ee];
    }
    __syncthreads();

    bf16x8 aa[2];
    #pragma unroll
    for (int kk = 0; kk < 2; ++kk){
      int row = w*16 + l15;
      aa[kk] = *(const bf16x8*)((const char*)Al + row*128 + ((lg*16 + kk*64) ^ ((row & 7) << 4)));
    }
    #pragma unroll
    for (int nb = 0; nb < 5; ++nb){
      #pragma unroll
      for (int kk = 0; kk < 2; ++kk){
        int row = nb*16 + l15;
        int sw = (((row & 7) ^ (row >> 3)) & 7) << 4;
        bf16x8 vb = *(const bf16x8*)((const char*)Vt + row*128 + ((lg*16 + kk*64) ^ sw));
        acc[nb] = __builtin_amdgcn_mfma_f32_16x16x32_bf16(aa[kk], vb, acc[nb], 0, 0, 0);
      }
    }
  }

  float* Pb = P + (size_t)(bh*NCHUNK + chunk) * 64 * 80;
  #pragma unroll
  for (int nb = 0; nb < 5; ++nb){
    #pragma unroll
    for (int r = 0; r < 4; ++r){
      int s = w*16 + lg*4 + r;
      Pb[(size_t)s*80 + nb*16 + l15] = acc[nb][r];
    }
  }
}

__global__ void reduce_out(const float* __restrict__ P, float* __restrict__ out){
  int flat = blockIdx.x * 256 + threadIdx.x;
  int c = flat & 63, s = (flat >> 6) & 63, bh = flat >> 12;
  int bb = bh >> 4, h = bh & 15;
  float sc = 0.f, sn = 0.f;
  #pragma unroll
  for (int ch = 0; ch < NCHUNK; ++ch){
    const float* base = P + ((size_t)(bh*NCHUNK + ch)*64 + s)*80;
    sc += base[c];
    sn += base[64];
  }
  out[((size_t)s*BATCH + bb)*1024 + h*64 + c] = sc / (sn + 0.001f);
}

extern "C" void kernel_launch(void* const* d_in, const int* in_sizes, int n_in,
                              void* d_out, int out_size, void* d_ws, size_t ws_size,
                              hipStream_t stream)
{
  const float* s  = (const float*)d_in[0];
  const float* d  = (const float*)d_in[1];
  const float* Wq = (const float*)d_in[2];
  const float* bq = (const float*)d_in[3];
  const float* Wk = (const float*)d_in[4];
  const float* bk = (const float*)d_in[5];
  const float* Wv = (const float*)d_in[6];
  const float* bv = (const float*)d_in[7];
  float* out = (float*)d_out;

  char* ws = (char*)d_ws;
  unsigned short* dbf = (unsigned short*)(ws);               // 67,108,864
  unsigned short* sbf = (unsigned short*)(ws + 67108864);    //  1,048,576
  unsigned short* wqb = (unsigned short*)(ws + 68157440);    //  2,097,152
  unsigned short* wkb = (unsigned short*)(ws + 70254592);    //  2,097,152 (Wk rows 0..1023)
  unsigned short* wvb = (unsigned short*)(ws + 72351744);    //  2,097,152 (Wv = wkb rows 1024..2047)
  unsigned short* Qw  = (unsigned short*)(ws + 74448896);    //  1,048,576
  unsigned short* Kw  = (unsigned short*)(ws + 75497472);    // 67,108,864
  unsigned short* Vw  = (unsigned short*)(ws + 142606336);   // 67,108,864
  float*          Pw  = (float*)(ws + 209715200);            // 20,971,520

  (void)in_sizes; (void)n_in; (void)out_size; (void)ws_size;

  cvt_all<<<36352, 256, 0, stream>>>(d, s, Wq, Wk, Wv, dbf, sbf, wqb, wkb, wvb);

  gemm_kvq<<<2064, 256, 0, stream>>>(dbf, sbf, wkb, wqb, bq, bk, bv, Qw, Kw, Vw);

  attn_kernel<<<dim3(128, NCHUNK), 256, 0, stream>>>(Qw, Kw, Vw, Pw);

  reduce_out<<<(TS*BATCH*HC)/256, 256, 0, stream>>>(Pw, out);
}

// Round 11
// 243.781 us; speedup vs baseline: 1.1378x; 1.0419x over previous
//
#include <hip/hip_runtime.h>

// SlotAttention on MI355X (gfx950).
// R10: consolidation. gemm reverted to the R2 structure (fastest measured:
// 256x256 tile, 8 waves, BK=32, 4-slot LDS ring, 1 counted-vmcnt barrier
// per K-tile) with the Q projection merged as 8 extra role-switched blocks
// (grid 1032 = 8x129). cvt fused (R4). attn/reduce unchanged.
// History: R2=160us is the best of 7 structurally distinct GEMM schedules
// (R3 reg-dbuf 190, R4 8-phase 163, R5 2-blk 170, R6 f32-stage 295,
// R7 A-reuse-8w 186, R8 B-direct 208, R9 A-reuse-4w 185) — this shape
// (K=1024) sits at the m97-class structure ceiling (~860 TF).

#define TS 64
#define TD 4096
#define BATCH 8
#define HC 1024
#define NHEAD 16
#define MD (TD*BATCH)   // 32768
#define MS (TS*BATCH)   // 512
#define NCHUNK 8
#define CHTOK (TD/NCHUNK) // 512

#define KTILES 32       // K=1024 / BK=32

typedef __attribute__((ext_vector_type(8))) __bf16 bf16x8;
typedef __attribute__((ext_vector_type(4))) float f32x4;
typedef __attribute__((ext_vector_type(4))) unsigned short u16x4;
typedef __attribute__((ext_vector_type(8))) unsigned short u16x8;

__device__ __forceinline__ unsigned short f2bf(float x){
  union { float f; unsigned u; } v; v.f = x;
  unsigned r = v.u + 0x7FFFu + ((v.u >> 16) & 1u);
  return (unsigned short)(r >> 16);
}

__device__ __forceinline__ void gll16(const void* g, void* l){
  __builtin_amdgcn_global_load_lds((__attribute__((address_space(1))) void*)g,
                                   (__attribute__((address_space(3))) void*)l, 16, 0, 0);
}

// Fused f32->bf16 convert for all five inputs (one launch).
__global__ void cvt_all(const float* __restrict__ d, const float* __restrict__ s,
                        const float* __restrict__ wq, const float* __restrict__ wk,
                        const float* __restrict__ wv,
                        unsigned short* __restrict__ dbf, unsigned short* __restrict__ sbf,
                        unsigned short* __restrict__ wqb, unsigned short* __restrict__ wkb,
                        unsigned short* __restrict__ wvb){
  long i = (long)blockIdx.x * 256 + threadIdx.x;
  const float* src; unsigned short* dst; long off;
  if (i < 8388608L)      { src = d;  dst = dbf; off = i; }
  else if (i < 8519680L) { src = s;  dst = sbf; off = i - 8388608L; }
  else if (i < 8781824L) { src = wq; dst = wqb; off = i - 8519680L; }
  else if (i < 9043968L) { src = wk; dst = wkb; off = i - 8781824L; }
  else                   { src = wv; dst = wvb; off = i - 9043968L; }
  f32x4 f = ((const f32x4*)src)[off];
  u16x4 o;
  o[0] = f2bf(f[0]); o[1] = f2bf(f[1]); o[2] = f2bf(f[2]); o[3] = f2bf(f[3]);
  ((u16x4*)dst)[off] = o;
}

// ---------------------------------------------------------------------------
// Unified QKV GEMM (R2 structure).
// kv-role (wg 0..1023): C[32768 x 2048] = dbf @ [Wk;Wv]^T + bias; tile
//   (mt,nt) = (wg>>3, wg&7); block's 256 cols uniformly K (nt<4) or V.
// q-role (wg 1024..1031): Q[512 x 1024] = sbf @ Wq^T + bq; qi = wg-1024,
//   (mt,nt) = (qi>>2, qi&3).
// 256x256 tile, BK=32, 8 waves (2Mx4N), per-wave 128x64.
// LDS: 4-slot ring of (A 16KB + B 16KB) = 128 KiB, tile t -> slot t&3.
// Staging runs 3 tiles ahead; ONE boundary per tile: counted vmcnt(8)
// (2 tiles in flight) + s_barrier. WAR-safe: slot (t+3)&3 == (t-1)&3 whose
// reads completed (consumed by MFMA) before the previous boundary barrier.
// 64B LDS rows, chunk XOR swizzle -> 0 bank conflicts (measured R2-R5).
// ---------------------------------------------------------------------------
__global__ __launch_bounds__(512, 2) void gemm_qkv(
    const unsigned short* __restrict__ A,     // dbf [32768][1024]
    const unsigned short* __restrict__ Sb,    // sbf [512][1024]
    const unsigned short* __restrict__ Wkv,   // [2048][1024] (Wk rows, then Wv)
    const unsigned short* __restrict__ Wq,    // [1024][1024]
    const float* __restrict__ bq,
    const float* __restrict__ bk,
    const float* __restrict__ bv,
    unsigned short* __restrict__ Qout,
    unsigned short* __restrict__ Kout,
    unsigned short* __restrict__ Vout)
{
  __shared__ unsigned short As[4][256*32];
  __shared__ unsigned short Bs[4][256*32];

  const int nwg = gridDim.x;                 // 1032 (= 8 x 129)
  const int cpx = nwg >> 3;
  const int orig = blockIdx.x;
  const int wg = (orig & 7) * cpx + (orig >> 3);   // bijective XCD swizzle
  const int tid = threadIdx.x;
  const int lane = tid & 63, w = tid >> 6;   // 8 waves
  const int l15 = lane & 15, lg = lane >> 4;
  const int wm = w >> 2, wn = w & 3;

  const bool isQ = (wg >= 1024);
  int mt, nt;
  const unsigned short* Ab; const unsigned short* Bb;
  if (!isQ){ mt = wg >> 3; nt = wg & 7; Ab = A;  Bb = Wkv; }
  else     { int qi = wg - 1024; mt = qi >> 2; nt = qi & 3; Ab = Sb; Bb = Wq; }

  // ---- staging addressing (pre-swizzled global source, linear LDS dest) ----
  const int lr = lane >> 2;                  // 0..15
  const int schunk = (((lane & 3) ^ ((lane >> 3) & 3)) << 4);
  const char* pa[2]; const char* pb[2]; unsigned ldso[2];
  #pragma unroll
  for (int j = 0; j < 2; ++j){
    int grow = j*128 + w*16 + lr;
    pa[j] = (const char*)Ab + (size_t)(mt*256 + grow)*2048 + schunk;
    pb[j] = (const char*)Bb + (size_t)(nt*256 + grow)*2048 + schunk;
    ldso[j] = (unsigned)(j*8192 + w*1024);   // wave-uniform; HW adds lane*16
  }

  #define STAGE_A(t) { char* dst = (char*)&As[(t)&3][0]; \
    gll16(pa[0] + (size_t)(t)*64, dst + ldso[0]); \
    gll16(pa[1] + (size_t)(t)*64, dst + ldso[1]); }
  #define STAGE_B(t) { char* dst = (char*)&Bs[(t)&3][0]; \
    gll16(pb[0] + (size_t)(t)*64, dst + ldso[0]); \
    gll16(pb[1] + (size_t)(t)*64, dst + ldso[1]); }

  // ---- fragment read offsets (swizzle: chunk = lg ^ ((row>>1)&3)) ----
  const unsigned cswz = ((unsigned)(lg ^ ((l15 >> 1) & 3))) << 4;
  const unsigned aoff = (unsigned)(wm*128 + l15)*64 + cswz;   // + mf*1024
  const unsigned boff = (unsigned)(wn*64  + l15)*64 + cswz;   // + nf*1024

  const f32x4 fz = {0.f, 0.f, 0.f, 0.f};
  f32x4 acc[8][4];
  #pragma unroll
  for (int m = 0; m < 8; ++m)
    #pragma unroll
    for (int n = 0; n < 4; ++n) acc[m][n] = fz;

  // ---- prologue: stage tiles 0,1,2; wait tile 0 (8 loads still in flight)
  STAGE_A(0) STAGE_B(0) STAGE_A(1) STAGE_B(1) STAGE_A(2) STAGE_B(2)
  asm volatile("s_waitcnt vmcnt(8)" ::: "memory");
  __builtin_amdgcn_s_barrier();
  __builtin_amdgcn_sched_barrier(0);

  #pragma unroll 1
  for (int t = 0; t < KTILES; ++t){
    const char* as = (const char*)&As[t & 3][0];
    const char* bs = (const char*)&Bs[t & 3][0];

    // ---- half 1: reads + stage-A(t+3), 16 MFMA (no barriers; waves drift)
    bf16x8 af0[4], bfr[4];
    #pragma unroll
    for (int mf = 0; mf < 4; ++mf) af0[mf] = *(const bf16x8*)(as + aoff + mf*1024u);
    #pragma unroll
    for (int nf = 0; nf < 4; ++nf) bfr[nf] = *(const bf16x8*)(bs + boff + nf*1024u);
    if (t + 3 < KTILES) STAGE_A(t + 3)
    __builtin_amdgcn_s_setprio(1);
    #pragma unroll
    for (int mf = 0; mf < 4; ++mf)
      #pragma unroll
      for (int nf = 0; nf < 4; ++nf)
        acc[mf][nf] = __builtin_amdgcn_mfma_f32_16x16x32_bf16(af0[mf], bfr[nf], acc[mf][nf], 0, 0, 0);
    __builtin_amdgcn_s_setprio(0);

    // ---- half 2: reads + stage-B(t+3), 16 MFMA
    bf16x8 af1[4];
    #pragma unroll
    for (int mf = 0; mf < 4; ++mf) af1[mf] = *(const bf16x8*)(as + aoff + (4 + mf)*1024u);
    if (t + 3 < KTILES) STAGE_B(t + 3)
    __builtin_amdgcn_s_setprio(1);
    #pragma unroll
    for (int mf = 0; mf < 4; ++mf)
      #pragma unroll
      for (int nf = 0; nf < 4; ++nf)
        acc[4 + mf][nf] = __builtin_amdgcn_mfma_f32_16x16x32_bf16(af1[mf], bfr[nf], acc[4 + mf][nf], 0, 0, 0);
    __builtin_amdgcn_s_setprio(0);

    // ---- tile boundary: counted vmcnt (never 0 until drain) + ONE barrier
    __builtin_amdgcn_sched_barrier(0);
    if (t < KTILES - 3)       { asm volatile("s_waitcnt vmcnt(8)" ::: "memory"); }
    else if (t == KTILES - 3) { asm volatile("s_waitcnt vmcnt(4)" ::: "memory"); }
    else if (t == KTILES - 2) { asm volatile("s_waitcnt vmcnt(0)" ::: "memory"); }
    __builtin_amdgcn_s_barrier();
    __builtin_amdgcn_sched_barrier(0);
  }

  // ---- epilogue: bias + bf16 store
  int ccol; unsigned short* Cb; const float* bias;
  if (isQ)         { Cb = Qout; bias = bq; ccol = nt*256 + wn*64; }
  else if (nt < 4) { Cb = Kout; bias = bk; ccol = (nt & 3)*256 + wn*64; }
  else             { Cb = Vout; bias = bv; ccol = (nt & 3)*256 + wn*64; }
  float bvv[4];
  #pragma unroll
  for (int nf = 0; nf < 4; ++nf) bvv[nf] = bias[ccol + nf*16 + l15];
  #pragma unroll
  for (int mf = 0; mf < 8; ++mf){
    #pragma unroll
    for (int r = 0; r < 4; ++r){
      size_t row = (size_t)(mt*256 + wm*128 + mf*16 + lg*4 + r);
      unsigned short* cp = Cb + row*1024 + ccol;
      #pragma unroll
      for (int nf = 0; nf < 4; ++nf)
        cp[nf*16 + l15] = f2bf(acc[mf][nf][r] + bvv[nf]);
    }
  }
  #undef STAGE_A
  #undef STAGE_B
}

// one block per (b*16+h, chunk). 256 threads = 4 waves; wave w owns slots [16w,16w+16).
__global__ __launch_bounds__(256) void attn_kernel(
    const unsigned short* __restrict__ Q,
    const unsigned short* __restrict__ K,
    const unsigned short* __restrict__ V,
    float* __restrict__ P)
{
  __shared__ unsigned short Qs[64*64];
  __shared__ unsigned short Ks[64*64];
  __shared__ unsigned short Vt[80*64];
  __shared__ unsigned short Al[64*64];
  __shared__ float red[256];

  const int bh = blockIdx.x;
  const int chunk = blockIdx.y;
  const int bb = bh >> 4, h = bh & 15;
  const int tid = threadIdx.x;
  const int lane = tid & 63, w = tid >> 6;
  const int l15 = lane & 15, lg = lane >> 4;
  const int lrow = lane >> 3, lch = (lane & 7) << 4;

  for (int i = tid; i < 16*64; i += 256){
    int r = i >> 6;
    Vt[(64 + r)*64 + (i & 63)] = (r == 0) ? (unsigned short)0x3F80 : (unsigned short)0;
  }

  #pragma unroll
  for (int j = 0; j < 2; ++j){
    int row = w*16 + j*8 + lrow;
    int sw = lch ^ ((row & 7) << 4);
    const char* g = (const char*)Q + (size_t)(row*BATCH + bb)*2048 + h*128 + sw;
    gll16(g, (char*)Qs + (w*16 + j*8)*128);
  }

  const f32x4 fz = {0.f, 0.f, 0.f, 0.f};
  f32x4 acc[5];
  #pragma unroll
  for (int nb = 0; nb < 5; ++nb) acc[nb] = fz;

  const int vtok = tid >> 2;
  const int vcg  = tid & 3;
  const int t0 = chunk * CHTOK;

  for (int tt = 0; tt < CHTOK/64; ++tt){
    const int tb = t0 + tt*64;
    #pragma unroll
    for (int j = 0; j < 2; ++j){
      int row = w*16 + j*8 + lrow;
      int sw = lch ^ ((row & 7) << 4);
      const char* g = (const char*)K + (size_t)((size_t)(tb + row)*BATCH + bb)*2048 + h*128 + sw;
      gll16(g, (char*)Ks + (w*16 + j*8)*128);
    }
    const char* vg = (const char*)V + (size_t)((size_t)(tb + vtok)*BATCH + bb)*2048 + h*128 + vcg*32;
    u16x8 v0 = *(const u16x8*)vg;
    u16x8 v1 = *(const u16x8*)(vg + 16);
    __syncthreads();

    bf16x8 qa[2];
    #pragma unroll
    for (int kk = 0; kk < 2; ++kk){
      int row = w*16 + l15;
      qa[kk] = *(const bf16x8*)((const char*)Qs + row*128 + ((lg*16 + kk*64) ^ ((row & 7) << 4)));
    }
    float e[4][4];
    #pragma unroll
    for (int nb = 0; nb < 4; ++nb){
      f32x4 s = fz;
      #pragma unroll
      for (int kk = 0; kk < 2; ++kk){
        int row = nb*16 + l15;
        bf16x8 kb = *(const bf16x8*)((const char*)Ks + row*128 + ((lg*16 + kk*64) ^ ((row & 7) << 4)));
        s = __builtin_amdgcn_mfma_f32_16x16x32_bf16(qa[kk], kb, s, 0, 0, 0);
      }
      #pragma unroll
      for (int r = 0; r < 4; ++r) e[nb][r] = __expf(s[r] * 0.125f);
    }
    #pragma unroll
    for (int nb = 0; nb < 4; ++nb){
      float cp = e[nb][0] + e[nb][1] + e[nb][2] + e[nb][3];
      cp += __shfl_xor(cp, 16);
      cp += __shfl_xor(cp, 32);
      if (lg == 0) red[w*64 + nb*16 + l15] = cp;
    }
    __syncthreads();

    #pragma unroll
    for (int nb = 0; nb < 4; ++nb){
      int col = nb*16 + l15;
      float dn = red[col] + red[64 + col] + red[128 + col] + red[192 + col];
      float inv = 1.0f / dn;
      #pragma unroll
      for (int r = 0; r < 4; ++r){
        int row = w*16 + lg*4 + r;
        Al[row*64 + ((((2*col)) ^ ((row & 7) << 4)) >> 1)] = f2bf(e[nb][r] * inv);
      }
    }
    #pragma unroll
    for (int ee = 0; ee < 8; ++ee){
      int c0 = vcg*16 + ee;
      int sw0 = (((c0 & 7) ^ (c0 >> 3)) & 7) << 4;
      Vt[c0*64 + (((2*vtok) ^ sw0) >> 1)] = v0[ee];
    }
    #pragma unroll
    for (int ee = 0; ee < 8; ++ee){
      int c1 = vcg*16 + 8 + ee;
      int sw1 = (((c1 & 7) ^ (c1 >> 3)) & 7) << 4;
      Vt[c1*64 + (((2*vtok) ^ sw1) >> 1)] = v1[ee];
    }
    __syncthreads();

    bf16x8 aa[2];
    #pragma unroll
    for (int kk = 0; kk < 2; ++kk){
      int row = w*16 + l15;
      aa[kk] = *(const bf16x8*)((const char*)Al + row*128 + ((lg*16 + kk*64) ^ ((row & 7) << 4)));
    }
    #pragma unroll
    for (int nb = 0; nb < 5; ++nb){
      #pragma unroll
      for (int kk = 0; kk < 2; ++kk){
        int row = nb*16 + l15;
        int sw = (((row & 7) ^ (row >> 3)) & 7) << 4;
        bf16x8 vb = *(const bf16x8*)((const char*)Vt + row*128 + ((lg*16 + kk*64) ^ sw));
        acc[nb] = __builtin_amdgcn_mfma_f32_16x16x32_bf16(aa[kk], vb, acc[nb], 0, 0, 0);
      }
    }
  }

  float* Pb = P + (size_t)(bh*NCHUNK + chunk) * 64 * 80;
  #pragma unroll
  for (int nb = 0; nb < 5; ++nb){
    #pragma unroll
    for (int r = 0; r < 4; ++r){
      int s = w*16 + lg*4 + r;
      Pb[(size_t)s*80 + nb*16 + l15] = acc[nb][r];
    }
  }
}

__global__ void reduce_out(const float* __restrict__ P, float* __restrict__ out){
  int flat = blockIdx.x * 256 + threadIdx.x;
  int c = flat & 63, s = (flat >> 6) & 63, bh = flat >> 12;
  int bb = bh >> 4, h = bh & 15;
  float sc = 0.f, sn = 0.f;
  #pragma unroll
  for (int ch = 0; ch < NCHUNK; ++ch){
    const float* base = P + ((size_t)(bh*NCHUNK + ch)*64 + s)*80;
    sc += base[c];
    sn += base[64];
  }
  out[((size_t)s*BATCH + bb)*1024 + h*64 + c] = sc / (sn + 0.001f);
}

extern "C" void kernel_launch(void* const* d_in, const int* in_sizes, int n_in,
                              void* d_out, int out_size, void* d_ws, size_t ws_size,
                              hipStream_t stream)
{
  const float* s  = (const float*)d_in[0];
  const float* d  = (const float*)d_in[1];
  const float* Wq = (const float*)d_in[2];
  const float* bq = (const float*)d_in[3];
  const float* Wk = (const float*)d_in[4];
  const float* bk = (const float*)d_in[5];
  const float* Wv = (const float*)d_in[6];
  const float* bv = (const float*)d_in[7];
  float* out = (float*)d_out;

  char* ws = (char*)d_ws;
  unsigned short* dbf = (unsigned short*)(ws);               // 67,108,864
  unsigned short* sbf = (unsigned short*)(ws + 67108864);    //  1,048,576
  unsigned short* wqb = (unsigned short*)(ws + 68157440);    //  2,097,152
  unsigned short* wkb = (unsigned short*)(ws + 70254592);    //  2,097,152 (Wk rows 0..1023)
  unsigned short* wvb = (unsigned short*)(ws + 72351744);    //  2,097,152 (Wv = wkb rows 1024..2047)
  unsigned short* Qw  = (unsigned short*)(ws + 74448896);    //  1,048,576
  unsigned short* Kw  = (unsigned short*)(ws + 75497472);    // 67,108,864
  unsigned short* Vw  = (unsigned short*)(ws + 142606336);   // 67,108,864
  float*          Pw  = (float*)(ws + 209715200);            // 20,971,520

  (void)in_sizes; (void)n_in; (void)out_size; (void)ws_size;

  cvt_all<<<36352, 256, 0, stream>>>(d, s, Wq, Wk, Wv, dbf, sbf, wqb, wkb, wvb);

  gemm_qkv<<<1032, 512, 0, stream>>>(dbf, sbf, wkb, wqb, bq, bk, bv, Qw, Kw, Vw);

  attn_kernel<<<dim3(128, NCHUNK), 256, 0, stream>>>(Qw, Kw, Vw, Pw);

  reduce_out<<<(TS*BATCH*HC)/256, 256, 0, stream>>>(Pw, out);
}